// Round 3
// baseline (411.312 us; speedup 1.0000x reference)
//
#include <hip/hip_runtime.h>
#include <hip/hip_bf16.h>

// GATNE-T fused inference kernel — fp32 in/out.
// Shapes: V=500000, T=4, D=32, E=128, A=32, B=8192, S=10.
// One block (128 threads = 2 waves) per batch element.
//
// R3 changes vs R2:
//  - float4 gathers: 8 lanes per 128B nte row (was 32 lanes x 4B)
//  - no LDS staging of indices/meta; broadcast loads + early base_emb issue
//  - 4 barriers (was 5)

constexpr int TT = 4;    // edge types
constexpr int DD = 32;   // edge embedding size
constexpr int EE = 128;  // embedding size
constexpr int AA = 32;   // attention dim
constexpr int SS = 10;   // neighbor samples

__global__ __launch_bounds__(128) void gatne_fused(
    const int*   __restrict__ targets,      // [B]
    const int*   __restrict__ types,        // [B]
    const int*   __restrict__ neighbors,    // [B,T,S]
    const float* __restrict__ base_emb,     // [V,E]
    const float* __restrict__ nte,          // [V,T,D]
    const float* __restrict__ tw,           // [T,D,E]
    const float* __restrict__ tw1,          // [T,D,A]
    const float* __restrict__ tw2,          // [T,A]
    float*       __restrict__ out)          // [B,E]
{
    const int b   = blockIdx.x;
    const int tid = threadIdx.x;        // 0..127
    const int g   = tid >> 3;           // group 0..15 (8 lanes each)
    const int li  = tid & 7;            // lane in group -> d-range li*4..li*4+3
    const int t   = g >> 2;             // edge type for gather
    const int j   = g & 3;              // s-phase: s = j, j+4, j+8(<10)

    __shared__ float s_agg[TT][DD];     // node_agg[t][d]
    __shared__ float s_scores[TT];
    __shared__ float s_natt[DD];
    __shared__ float s_part[2];

    // Broadcast loads (wave-uniform address -> single request) issued early.
    const int ty = types[b];
    const int tg = targets[b];
    const float bval = base_emb[(long long)tg * EE + tid];   // overlaps gathers

    // ---- 1) node_agg[t][d] = mean_s nte[nb[t][s]][t][d] ----
    const int base_nb = b * (TT * SS) + t * SS;
    const int v0 = neighbors[base_nb + j];
    const int v1 = neighbors[base_nb + j + 4];
    const int v2 = (j < 2) ? neighbors[base_nb + j + 8] : 0;

    const float4* __restrict__ nte4 = (const float4*)nte;  // row stride 32 f4
    const int fo = t * 8 + li;  // float4 offset of [t][li*4] within a row
    float4 a0 = nte4[(long long)v0 * 32 + fo];
    float4 a1 = nte4[(long long)v1 * 32 + fo];
    float ax = a0.x + a1.x, ay = a0.y + a1.y, az = a0.z + a1.z, aw = a0.w + a1.w;
    if (j < 2) {
        float4 a2 = nte4[(long long)v2 * 32 + fo];
        ax += a2.x; ay += a2.y; az += a2.z; aw += a2.w;
    }
    // reduce across the 4 s-phase groups (stride 8 within each 32-lane block)
    ax += __shfl_xor(ax, 8, 64);  ay += __shfl_xor(ay, 8, 64);
    az += __shfl_xor(az, 8, 64);  aw += __shfl_xor(aw, 8, 64);
    ax += __shfl_xor(ax, 16, 64); ay += __shfl_xor(ay, 16, 64);
    az += __shfl_xor(az, 16, 64); aw += __shfl_xor(aw, 16, 64);
    if (j == 0) {
        float4 m = make_float4(ax * 0.1f, ay * 0.1f, az * 0.1f, aw * 0.1f);
        ((float4*)&s_agg[t][0])[li] = m;
    }
    __syncthreads();

    // ---- 2) u[t][a] = tanh(sum_d agg[t][d] * tw1[ty][d][a]) ; score[t] ----
    const int t2   = tid >> 5;          // 0..3
    const int lane = tid & 31;          // a index
    float ua = 0.f;
    #pragma unroll
    for (int d = 0; d < DD; ++d)
        ua += s_agg[t2][d] * tw1[ty * (DD * AA) + d * AA + lane];
    ua = tanhf(ua);

    float p = ua * tw2[ty * AA + lane];
    #pragma unroll
    for (int m = 16; m >= 1; m >>= 1)
        p += __shfl_xor(p, m, 64);
    if (lane == 0) s_scores[t2] = p;
    __syncthreads();

    // ---- 3) softmax over T=4 (redundant per thread) ----
    const float sc0 = s_scores[0], sc1 = s_scores[1];
    const float sc2 = s_scores[2], sc3 = s_scores[3];
    const float mx  = fmaxf(fmaxf(sc0, sc1), fmaxf(sc2, sc3));
    const float e0 = __expf(sc0 - mx), e1 = __expf(sc1 - mx);
    const float e2 = __expf(sc2 - mx), e3 = __expf(sc3 - mx);
    const float inv_sum = 1.f / (e0 + e1 + e2 + e3);

    // ---- 4) node_att[d] = sum_t att[t] * agg[t][d] ----
    if (tid < DD) {
        s_natt[tid] = (e0 * s_agg[0][tid] + e1 * s_agg[1][tid] +
                       e2 * s_agg[2][tid] + e3 * s_agg[3][tid]) * inv_sum;
    }
    __syncthreads();

    // ---- 5) proj[e] = sum_d natt[d] * tw[ty][d][e] ; + base ; l2 norm ----
    float val = 0.f;
    #pragma unroll
    for (int d = 0; d < DD; ++d)
        val += s_natt[d] * tw[ty * (DD * EE) + d * EE + tid];
    val += bval;

    float sq = val * val;
    #pragma unroll
    for (int m = 32; m >= 1; m >>= 1)
        sq += __shfl_xor(sq, m, 64);
    if ((tid & 63) == 0) s_part[tid >> 6] = sq;
    __syncthreads();
    const float inv = rsqrtf(fmaxf(s_part[0] + s_part[1], 1e-12f));

    out[b * EE + tid] = val * inv;
}

extern "C" void kernel_launch(void* const* d_in, const int* in_sizes, int n_in,
                              void* d_out, int out_size, void* d_ws, size_t ws_size,
                              hipStream_t stream) {
    const int*   targets   = (const int*)d_in[0];
    const int*   types     = (const int*)d_in[1];
    const int*   neighbors = (const int*)d_in[2];
    const float* base_emb  = (const float*)d_in[3];
    const float* nte       = (const float*)d_in[4];
    const float* tw        = (const float*)d_in[5];
    const float* tw1       = (const float*)d_in[6];
    const float* tw2       = (const float*)d_in[7];
    float*       out       = (float*)d_out;

    const int B = in_sizes[0];   // 8192
    (void)n_in; (void)out_size; (void)d_ws; (void)ws_size;

    gatne_fused<<<B, 128, 0, stream>>>(targets, types, neighbors,
                                       base_emb, nte, tw, tw1, tw2, out);
}